// Round 1
// baseline (300.007 us; speedup 1.0000x reference)
//
#include <hip/hip_runtime.h>
#include <hip/hip_bf16.h>

// Beamform: 4 channels of interleaved complex f32, per-block (4x5) complex
// combine with a (1x4) complex weight vector bf.
// Block b (global) = channel ch = b/blocksPerChannel, local block bl.
// Input floats for block: in_ch[bl*40 .. bl*40+39] (contiguous, 16B aligned).
// Output: out[b*10 .. b*10+9] = [re(c=0..4), im(c=0..4)].

__global__ __launch_bounds__(256) void beamform_kernel(
    const float* __restrict__ in0, const float* __restrict__ in1,
    const float* __restrict__ in2, const float* __restrict__ in3,
    const float* __restrict__ bf, float* __restrict__ out,
    int blocksPerChannel)
{
    const int bl = blockIdx.x * blockDim.x + threadIdx.x;  // local block in channel
    if (bl >= blocksPerChannel) return;
    const int ch = blockIdx.y;                             // channel 0..3

    const float* in = (ch == 0) ? in0 : (ch == 1) ? in1 : (ch == 2) ? in2 : in3;

    // Load 40 consecutive floats (10 aligned float4s).
    const float4* p = reinterpret_cast<const float4*>(in + (size_t)bl * 40);
    float x[40];
#pragma unroll
    for (int k = 0; k < 10; ++k) {
        float4 v = p[k];
        x[4 * k + 0] = v.x;
        x[4 * k + 1] = v.y;
        x[4 * k + 2] = v.z;
        x[4 * k + 3] = v.w;
    }

    // Beamforming weights (uniform across all threads; L1/L3 cached).
    float br[4], bi[4];
#pragma unroll
    for (int r = 0; r < 4; ++r) {
        br[r] = bf[2 * r];
        bi[r] = bf[2 * r + 1];
    }

    float o[10];
#pragma unroll
    for (int c = 0; c < 5; ++c) {
        float re = 0.f, im = 0.f;
#pragma unroll
        for (int r = 0; r < 4; ++r) {
            const float xr = x[10 * r + 2 * c];
            const float xi = x[10 * r + 2 * c + 1];
            re += br[r] * xr - bi[r] * xi;
            im += bi[r] * xr + br[r] * xi;
        }
        o[c] = re;
        o[5 + c] = im;
    }

    // Store 10 floats (5 aligned float2s). Output block index = ch*bpc + bl.
    const size_t b = (size_t)ch * blocksPerChannel + bl;
    float2* q = reinterpret_cast<float2*>(out + b * 10);
#pragma unroll
    for (int k = 0; k < 5; ++k) {
        q[k] = make_float2(o[2 * k], o[2 * k + 1]);
    }
}

extern "C" void kernel_launch(void* const* d_in, const int* in_sizes, int n_in,
                              void* d_out, int out_size, void* d_ws, size_t ws_size,
                              hipStream_t stream)
{
    const float* in0 = (const float*)d_in[0];
    const float* in1 = (const float*)d_in[1];
    const float* in2 = (const float*)d_in[2];
    const float* in3 = (const float*)d_in[3];
    const float* bf  = (const float*)d_in[4];
    float* out = (float*)d_out;

    const int len = in_sizes[0];              // 20,000,000 interleaved floats
    const int blocksPerChannel = len / 40;    // 500,000 blocks of 20 complex samples

    const int block = 256;
    dim3 grid((blocksPerChannel + block - 1) / block, 4, 1);
    beamform_kernel<<<grid, dim3(block, 1, 1), 0, stream>>>(
        in0, in1, in2, in3, bf, out, blocksPerChannel);
}

// Round 2
// 286.992 us; speedup vs baseline: 1.0454x; 1.0454x over previous
//
#include <hip/hip_runtime.h>
#include <hip/hip_bf16.h>

// Beamform: 4 channels of interleaved complex f32; per 20-complex-sample block
// a (1x4)@(4x5) complex combine with weight vector bf (8 floats, re/im interleaved).
//
// Work mapping (round 2): 5 threads per block, thread = (bl, c), c in [0,5).
// Thread reads 4 float2 pairs x[10r+2c .. 10r+2c+1] (r=0..3) from
// in_ch[bl*40 ...]; wave's 64 lanes cover 2048 contiguous bytes per load inst
// (16 lines vs 64 lines for the round-1 one-thread-per-block mapping).
// Output block b=ch*bpc+bl: out[b*10 + c] = re, out[b*10 + 5 + c] = im.

__global__ __launch_bounds__(256) void beamform_kernel(
    const float* __restrict__ in0, const float* __restrict__ in1,
    const float* __restrict__ in2, const float* __restrict__ in3,
    const float* __restrict__ bf, float* __restrict__ out,
    int blocksPerChannel, int threadsPerChannel)
{
    const int tid = blockIdx.x * blockDim.x + threadIdx.x;  // 0 .. 5*bpc-1
    if (tid >= threadsPerChannel) return;
    const int ch = blockIdx.y;  // channel 0..3

    const float* __restrict__ in =
        (ch == 0) ? in0 : (ch == 1) ? in1 : (ch == 2) ? in2 : in3;

    const int bl = tid / 5;         // block within channel (magic-mul div)
    const int c  = tid - bl * 5;    // column 0..4

    // 4 aligned float2 loads: x[10r+2c], x[10r+2c+1]
    const float2* __restrict__ p =
        reinterpret_cast<const float2*>(in + (size_t)bl * 40 + 2 * c);
    // p is float2-indexed: element (10r+2c)/2 = 5r + c relative to bl*20
    const float2 x0 = p[0];
    const float2 x1 = p[5];
    const float2 x2 = p[10];
    const float2 x3 = p[15];

    // Uniform beamforming weights (cached).
    const float br0 = bf[0], bi0 = bf[1];
    const float br1 = bf[2], bi1 = bf[3];
    const float br2 = bf[4], bi2 = bf[5];
    const float br3 = bf[6], bi3 = bf[7];

    float re = br0 * x0.x - bi0 * x0.y;
    float im = bi0 * x0.x + br0 * x0.y;
    re += br1 * x1.x - bi1 * x1.y;
    im += bi1 * x1.x + br1 * x1.y;
    re += br2 * x2.x - bi2 * x2.y;
    im += bi2 * x2.x + br2 * x2.y;
    re += br3 * x3.x - bi3 * x3.y;
    im += bi3 * x3.x + br3 * x3.y;

    const size_t b = (size_t)ch * blocksPerChannel + bl;
    float* __restrict__ o = out + b * 10;
    o[c] = re;
    o[5 + c] = im;
}

extern "C" void kernel_launch(void* const* d_in, const int* in_sizes, int n_in,
                              void* d_out, int out_size, void* d_ws, size_t ws_size,
                              hipStream_t stream)
{
    const float* in0 = (const float*)d_in[0];
    const float* in1 = (const float*)d_in[1];
    const float* in2 = (const float*)d_in[2];
    const float* in3 = (const float*)d_in[3];
    const float* bf  = (const float*)d_in[4];
    float* out = (float*)d_out;

    const int len = in_sizes[0];               // 20,000,000 interleaved floats
    const int blocksPerChannel = len / 40;     // 500,000 blocks / channel
    const int threadsPerChannel = blocksPerChannel * 5;

    const int block = 256;
    dim3 grid((threadsPerChannel + block - 1) / block, 4, 1);
    beamform_kernel<<<grid, dim3(block, 1, 1), 0, stream>>>(
        in0, in1, in2, in3, bf, out, blocksPerChannel, threadsPerChannel);
}